// Round 1
// baseline (174.209 us; speedup 1.0000x reference)
//
#include <hip/hip_runtime.h>

// HistogramLoss_2channel: FUSED single-kernel version (R7).
//
// Prior model (R2..R6): fixed per-replay floor ~63-65us (graph/harness),
// controllable GPU time ~6-8us across TWO kernel nodes. This round removes
// one graph node by fusing scatter+loss with a grid-wide spin barrier.
//
// Sparsity: triangle half-width 1/255 < bin spacing 1/128 => each pixel value
// hits <=2 of 256 bins; per-pixel 2D outer product has <=4 nonzeros (~1.016
// atomics/pixel-item, ~266K total).
//
// Signed-diff trick: inp scatters +w, ref scatters -w into ONE diff histogram
// per (replica,batch); loss needs only |h_inp - h_gt|.
//
// Grid barrier (poison-safe, reset-free):
//  - monotonic DOUBLE counter in d_ws. Each block atomicAdd(+1.0); target =
//    (floor((old+0.5)/1024)+1)*1024. The 0xAA poison (-3.7e-103 as double)
//    is absorbed by the first add and neutralized by the +0.5 in floor.
//    No reset => no reset/spin race across replays. double stays exact to
//    2^53 (a float counter would deadlock after 16384 replays).
//  - residency: 1024 blocks x 256thr, 0 LDS, __launch_bounds__(256,4)
//    => >=4 blocks/CU capacity x 256 CU = 2x margin over 1024 blocks.
//  - blocks 512..1023 arrive but don't spin (no phase-2 work).
//  - bounded spin guard: a hypothetical barrier failure becomes a wrong
//    answer (caught by verification), not a hang.
//
// Cross-XCD visibility WITHOUT a kernel boundary: scatter uses device-scope
// atomicAdd (coherent point); phase-2 reads/rezeros use AGENT-scope
// __hip_atomic_load/store so they can't hit a stale per-XCD L2 line;
// __threadfence() on both sides of the barrier.
//
// Replay safety: phase 2 re-zeros each bin after its single read (first-ever
// launch sees 0xAA poison = ~-3e-13f per bin, perturbing loss ~1e-17 --
// far below the 5.3e-9 threshold). Counter is monotonic, never reset.

#define NPIX 65536   // 256*256 pixels
#define BINS 256
#define REPL 4
#define HSZ  (2 * NPIX)          // one replica: 2 batches x 256x256 diff bins
#define NBLK 1024
#define NTHR 256

__global__ void __launch_bounds__(NTHR, 4)
fused_hist_loss_kernel(const float* __restrict__ inp,
                       const float* __restrict__ ref,
                       float* __restrict__ hist,
                       double* __restrict__ cnt,
                       float* __restrict__ out) {
    // ---------------- phase 1: sparse scatter ----------------
    int gid = blockIdx.x * NTHR + threadIdx.x;   // 4*65536 items
    int pix = gid & (NPIX - 1);
    int bb  = (gid >> 16) & 1;   // batch
    int im  = gid >> 17;         // 0 = inp (+), 1 = ref (-)
    const float* src = im ? ref : inp;
    float sgn = im ? -1.f : 1.f;
    // layout [B,2,H,W]: channel 0 -> ha (r dim), channel 1 -> hb (j dim)
    float x0 = src[bb * (2 * NPIX) + pix];
    float x1 = src[bb * (2 * NPIX) + NPIX + pix];
    float* h = hist + (blockIdx.x & (REPL - 1)) * HSZ + bb * (BINS * BINS);

    // reference: u=(x+1)/2, a1 = u + 1 - k/128, w = relu(1 - |a1|*255)
    //          = relu(1 - |t - k| * (255/128)) with t = 64x + 192
    float t0 = 64.f * x0 + 192.f;
    float t1 = 64.f * x1 + 192.f;
    int k0 = (int)floorf(t0);
    int k1 = (int)floorf(t1);

    float wr[2]; int ir[2]; int nr = 0;
    #pragma unroll
    for (int d = 0; d < 2; ++d) {
        int k = k0 + d;
        float w = 1.f - fabsf(t0 - (float)k) * 1.9921875f;  // 255/128 exact
        if (w > 0.f && k >= 0 && k < BINS) { wr[nr] = w; ir[nr] = k; ++nr; }
    }
    float wj[2]; int ij[2]; int nj = 0;
    #pragma unroll
    for (int d = 0; d < 2; ++d) {
        int k = k1 + d;
        float w = 1.f - fabsf(t1 - (float)k) * 1.9921875f;
        if (w > 0.f && k >= 0 && k < BINS) { wj[nj] = w * sgn; ij[nj] = k; ++nj; }
    }
    for (int a = 0; a < nj; ++a)
        for (int b = 0; b < nr; ++b)
            atomicAdd(&h[ij[a] * BINS + ir[b]], wj[a] * wr[b]);

    // ---------------- grid barrier ----------------
    __threadfence();            // order hist atomics before arrival
    __syncthreads();            // whole block's scatter done
    if (threadIdx.x == 0) {
        double old = atomicAdd(cnt, 1.0);   // device-scope arrive
        if (blockIdx.x < (2 * NPIX) / NTHR) {
            // this block has phase-2 work: spin until all NBLK arrived this
            // generation. target = next multiple of NBLK above old.
            double target = (floor((old + 0.5) * (1.0 / NBLK)) + 1.0) * (double)NBLK;
            int guard = 0;
            while (__hip_atomic_load(cnt, __ATOMIC_RELAXED,
                                     __HIP_MEMORY_SCOPE_AGENT) < target) {
                __builtin_amdgcn_s_sleep(1);
                if (++guard > (1 << 22)) break;  // fail loud, not hung
            }
        }
    }
    __syncthreads();
    if (blockIdx.x >= (2 * NPIX) / NTHR) return;  // arrived, no phase-2 work
    __threadfence();            // acquire side

    // ---------------- phase 2: loss + re-zero ----------------
    // gid in [0, 131072) here (blocks 0..511)
    int jr = gid & (NPIX - 1);
    int b2 = gid >> 16;
    float s = 0.f;
    #pragma unroll
    for (int r = 0; r < REPL; ++r) {
        float* p = &hist[r * HSZ + b2 * (BINS * BINS) + jr];
        // AGENT-scope load/store: bypass potentially-stale per-XCD L2
        s += __hip_atomic_load(p, __ATOMIC_RELAXED, __HIP_MEMORY_SCOPE_AGENT);
        __hip_atomic_store(p, 0.f, __ATOMIC_RELAXED, __HIP_MEMORY_SCOPE_AGENT);
    }
    const float inv = 1.f / 65536.f;                 // 1/(H*W), exact pow2
    float mann = fabsf(s) * inv;
    // Huber: mann < delta -> 0.5*mann^2/delta ; else mann - 0.5*delta
    float loss = (mann < 0.01f) ? (50.f * mann * mann) : (mann - 0.005f);
    out[gid] = loss;
}

extern "C" void kernel_launch(void* const* d_in, const int* in_sizes, int n_in,
                              void* d_out, int out_size, void* d_ws, size_t ws_size,
                              hipStream_t stream) {
    const float* inp = (const float*)d_in[0];
    const float* ref = (const float*)d_in[1];
    float* hist = (float*)d_ws;                     // REPL*2*65536 floats = 2 MiB
    double* cnt = (double*)((char*)d_ws + REPL * HSZ * sizeof(float)); // 8B-aligned
    float* out  = (float*)d_out;                    // 2*1*256*256 floats

    fused_hist_loss_kernel<<<NBLK, NTHR, 0, stream>>>(inp, ref, hist, cnt, out);
}

// Round 2
// 69.912 us; speedup vs baseline: 2.4918x; 2.4918x over previous
//
#include <hip/hip_runtime.h>

// HistogramLoss_2channel: sparse soft-histogram, 2-kernel chain, SIGNED
// difference histogram.  (R8: revert of the R7 fusion regression.)
//
// R7 post-mortem: fusing scatter+loss behind an in-kernel grid barrier cost
// +120us, not -3us. The barrier's coherent-line ping-pong (1024 arrivals +
// 512 AGENT-scope spinners on one line across 8 XCDs) plus uncached AGENT
// phase-2 traffic (10.7MB write-through vs 2.5MB cached) dwarfed the ~2-4us
// of saved graph-node overhead. On MI355X a kernel boundary IS the cheap
// grid barrier for small kernels. Structure below is the verified R6 winner
// (69.7us) with one safe tweak: float4-vectorized loss kernel (128 blocks).
//
// Sparsity: triangle half-width 1/255 < bin spacing 1/128 => each pixel value
// hits <=2 of 256 bins; per-pixel 2D outer product has <=4 nonzeros (~1.016
// atomics/pixel-item, ~266K total).
//
// Signed-diff trick: loss needs only |h_inp - h_gt|, so inp scatters +w and
// ref scatters -w into ONE diff histogram per (replica,batch). Halves hist
// memory and halves the loss kernel's read+rezero traffic.
//
// Replay safety (R1: d_ws is NOT re-poisoned between graph replays): the
// loss kernel re-zeros each bin after its single read, restoring zeros for
// the next replay. First-ever launch sees 0xAA poison = -1.5e-13f per bin,
// perturbing the loss ~5e-18 -- 9 orders below the 5.3e-9 threshold.
//
// Occupancy lesson (R5): scatter stays at 1024 blocks (256-block variant
// regressed). REPL=4 replica spread via blockIdx&3 for line-conflict relief.
//
// Session model (R2..R7): fixed per-replay floor ~63-65us (graph/harness),
// controllable GPU time ~6-8us. Launch-overhead bound; ~1us of actual data
// movement. R7 proved the two-node structure is already minimal-cost.

#define NPIX 65536   // 256*256 pixels
#define BINS 256
#define REPL 4
#define HSZ  (2 * NPIX)          // one replica: 2 batches x 256x256 diff bins

__global__ void __launch_bounds__(256)
scatter_kernel(const float* __restrict__ inp,
               const float* __restrict__ ref,
               float* __restrict__ hist) {
    int gid = blockIdx.x * blockDim.x + threadIdx.x;   // 4*65536 threads
    int pix = gid & (NPIX - 1);
    int bb  = (gid >> 16) & 1;   // batch
    int im  = gid >> 17;         // 0 = inp (+), 1 = ref (-)
    const float* src = im ? ref : inp;
    float sgn = im ? -1.f : 1.f;
    // layout [B,2,H,W]: channel 0 -> ha (r dim), channel 1 -> hb (j dim)
    float x0 = src[bb * (2 * NPIX) + pix];
    float x1 = src[bb * (2 * NPIX) + NPIX + pix];
    float* h = hist + (blockIdx.x & (REPL - 1)) * HSZ + bb * (BINS * BINS);

    // reference: u=(x+1)/2, a1 = u + 1 - k/128, w = relu(1 - |a1|*255)
    //          = relu(1 - |t - k| * (255/128)) with t = 64x + 192
    float t0 = 64.f * x0 + 192.f;
    float t1 = 64.f * x1 + 192.f;
    int k0 = (int)floorf(t0);
    int k1 = (int)floorf(t1);

    float wr[2]; int ir[2]; int nr = 0;
    #pragma unroll
    for (int d = 0; d < 2; ++d) {
        int k = k0 + d;
        float w = 1.f - fabsf(t0 - (float)k) * 1.9921875f;  // 255/128 exact
        if (w > 0.f && k >= 0 && k < BINS) { wr[nr] = w; ir[nr] = k; ++nr; }
    }
    float wj[2]; int ij[2]; int nj = 0;
    #pragma unroll
    for (int d = 0; d < 2; ++d) {
        int k = k1 + d;
        float w = 1.f - fabsf(t1 - (float)k) * 1.9921875f;
        if (w > 0.f && k >= 0 && k < BINS) { wj[nj] = w * sgn; ij[nj] = k; ++nj; }
    }
    for (int a = 0; a < nj; ++a)
        for (int b = 0; b < nr; ++b)
            atomicAdd(&h[ij[a] * BINS + ir[b]], wj[a] * wr[b]);
}

__global__ void __launch_bounds__(256)
loss_rezero_kernel(float* __restrict__ hist,
                   float* __restrict__ out) {
    // float4-vectorized: 32768 threads, each owns 4 consecutive bins.
    int gid = blockIdx.x * blockDim.x + threadIdx.x;   // 0..32767
    int bb  = gid >> 14;             // 16384 float4-items per batch
    int jr4 = (gid & 16383) << 2;    // bin index (multiple of 4)
    float4 s = make_float4(0.f, 0.f, 0.f, 0.f);
    #pragma unroll
    for (int r = 0; r < REPL; ++r) {
        float4* p = (float4*)&hist[r * HSZ + bb * (BINS * BINS) + jr4];
        float4 v = *p;
        s.x += v.x; s.y += v.y; s.z += v.z; s.w += v.w;
        *p = make_float4(0.f, 0.f, 0.f, 0.f);  // re-zero for next replay
    }
    const float inv = 1.f / 65536.f;                 // 1/(H*W), exact pow2
    // Huber: mann < delta -> 0.5*mann^2/delta ; else mann - 0.5*delta
    float4 l; float m;
    m = fabsf(s.x) * inv; l.x = (m < 0.01f) ? (50.f * m * m) : (m - 0.005f);
    m = fabsf(s.y) * inv; l.y = (m < 0.01f) ? (50.f * m * m) : (m - 0.005f);
    m = fabsf(s.z) * inv; l.z = (m < 0.01f) ? (50.f * m * m) : (m - 0.005f);
    m = fabsf(s.w) * inv; l.w = (m < 0.01f) ? (50.f * m * m) : (m - 0.005f);
    *(float4*)&out[bb * (BINS * BINS) + jr4] = l;
}

extern "C" void kernel_launch(void* const* d_in, const int* in_sizes, int n_in,
                              void* d_out, int out_size, void* d_ws, size_t ws_size,
                              hipStream_t stream) {
    const float* inp = (const float*)d_in[0];
    const float* ref = (const float*)d_in[1];
    float* hist = (float*)d_ws;                // REPL * 2 * 65536 floats = 2 MiB
    float* out  = (float*)d_out;               // 2*1*256*256 floats

    scatter_kernel<<<(4 * NPIX) / 256, 256, 0, stream>>>(inp, ref, hist);
    loss_rezero_kernel<<<(2 * NPIX) / (4 * 256), 256, 0, stream>>>(hist, out);
}